// Round 2
// baseline (870.113 us; speedup 1.0000x reference)
//
#include <hip/hip_runtime.h>
#include <math.h>

// Problem: B=32, A=2048, D2=2048 (two heads of D=1024), TOP_K=5, fp32.
// a_embeds_target = 512 MB read per call >> all else -> HBM-bound.
// Roofline: 512 MB / 6.3 TB/s ~= 81 us for kernel 1; kernel 2 reads 768 KB.
//
// R1 post-mortem: dur_us includes ~500 us harness reset (2 GiB ws 0xAA fill
// ~330 us [counter-verified 6.5 TB/s] + 512 MB d_in restore).
// R2 post-mortem: pipeline+nt rewrite = -7 us (neutral). Two worlds:
//   (a) kernel1 ~165 us (~3.2 TB/s) with an unexplained cap, or
//   (b) kernel1 ~90 us (at BW ceiling) and the restore costs more than the
//       assumed 160 us. All structural variants within 7 us favors (b), but
//       kernel1 has NEVER been visible in top-5 counters (fills ~330 us
//       occupy all slots).
//
// R3 = MEASUREMENT ROUND (deliberate, will be reverted): run the logits body
// 4x in one dispatch. Pass 0 -> real logits. Passes 1-3 read batch-rotated
// rows (same 512 MB total, not CSE-able) and write to dummy ws regions.
// Dispatch dur = 4*T1 >= ~370 us -> cracks top-5 -> direct readout of
// T1 = dur/4, read BW = FETCH_SIZE/dur, plus VALUBusy/Occupancy diagnosis.
#define BATCH 32
#define NACT  2048
#define DIM2  2048   // 2*D
#define TOPK  5
#define ACTIONS_PER_BLOCK 32   // 4 waves x 8 actions
#define APW   8                // actions per wave
#define NPASS 4                // measurement passes (revert to 1 after R3)

typedef float floatx4 __attribute__((ext_vector_type(4)));

// ---------------------------------------------------------------------------
// Kernel 1: logits[h][b][a] = dot(s[b, hD:(h+1)D], a_emb[b, a, hD:(h+1)D]).
// One wave per 8 actions. Lane l owns columns l*4 + 256*i (i=0..7) as float4.
// 2-deep double-buffered pipeline, nontemporal stream loads, deferred
// butterfly reductions. Wrapped in NPASS measurement loop (see header).
// ---------------------------------------------------------------------------
__global__ __launch_bounds__(256) void logits_kernel(
    const float* __restrict__ s_embed,   // [B, DIM2]
    const float* __restrict__ a_emb,     // [B, A, DIM2]
    float* __restrict__ logits)          // [2, B, A] in ws (+ dummy regions)
{
    const int tile  = blockIdx.x;                 // 32*64 tiles
    const int b     = tile >> 6;                  // NACT/ACTIONS_PER_BLOCK=64
    const int a0    = (tile & 63) * ACTIONS_PER_BLOCK;
    const int wave  = threadIdx.x >> 6;
    const int lane  = threadIdx.x & 63;

    // s_embed[b] fragment for this lane: 8 x float4 = 32 floats in VGPRs.
    floatx4 sreg[8];
    const float* srow = s_embed + (size_t)b * DIM2 + lane * 4;
    #pragma unroll
    for (int i = 0; i < 8; ++i)
        sreg[i] = *(const floatx4*)(srow + 256 * i);

    const int abase = a0 + wave * APW;

    #pragma unroll 1
    for (int pass = 0; pass < NPASS; ++pass) {
        asm volatile("" ::: "memory");            // no load CSE across passes
        // Pass 0 reads batch b (real). Passes 1-3 read rotated batch rows:
        // same aggregate 512 MB stream per pass, provably distinct addresses.
        const int bb = (b + pass) & 31;
        const float* pbase =
            a_emb + ((size_t)bb * NACT + abase) * DIM2 + lane * 4;

        float acc1[APW], acc2[APW];
        floatx4 bufA[8], bufB[8];

        #pragma unroll
        for (int i = 0; i < 8; ++i)
            bufA[i] = __builtin_nontemporal_load((const floatx4*)(pbase + 256 * i));

        #pragma unroll
        for (int j = 0; j < APW; ++j) {
            const floatx4* cur = (j & 1) ? bufB : bufA;   // folds after unroll
            floatx4*       nxt = (j & 1) ? bufA : bufB;

            if (j + 1 < APW) {
                const float* pn = pbase + (size_t)(j + 1) * DIM2;
                #pragma unroll
                for (int i = 0; i < 8; ++i)
                    nxt[i] = __builtin_nontemporal_load((const floatx4*)(pn + 256 * i));
            }

            float d1 = 0.f, d2 = 0.f;
            #pragma unroll
            for (int i = 0; i < 4; ++i) {                 // head 1
                floatx4 v = cur[i];
                d1 += v.x * sreg[i].x + v.y * sreg[i].y + v.z * sreg[i].z + v.w * sreg[i].w;
            }
            #pragma unroll
            for (int i = 4; i < 8; ++i) {                 // head 2
                floatx4 v = cur[i];
                d2 += v.x * sreg[i].x + v.y * sreg[i].y + v.z * sreg[i].z + v.w * sreg[i].w;
            }
            acc1[j] = d1;
            acc2[j] = d2;
        }

        // Batched butterfly reductions: 16 independent chains.
        #pragma unroll
        for (int off = 32; off >= 1; off >>= 1) {
            #pragma unroll
            for (int j = 0; j < APW; ++j) {
                acc1[j] += __shfl_xor(acc1[j], off, 64);
                acc2[j] += __shfl_xor(acc2[j], off, 64);
            }
        }

        if (lane == 0) {
            // pass 0 -> real logits; passes 1-3 -> dummy regions 64 MB apart
            // (ws is 2 GiB, counter-verified; real logits uses first 512 KB).
            float* o1 = logits + (size_t)pass * 16777216
                               + (size_t)b * NACT + abase;
            float* o2 = o1 + (size_t)BATCH * NACT;
            #pragma unroll
            for (int j = 0; j < APW; ++j) { o1[j] = acc1[j]; o2[j] = acc2[j]; }
        }
    }
}

// ---------------------------------------------------------------------------
// Kernel 2: one wave per (head,row). Row (2048 floats) in registers.
// 5x shfl-argmax (lowest-index tie-break), masked LSE with UNMASKED-max
// stabilizer and eps clamp. No LDS, no __syncthreads. (unchanged)
// ---------------------------------------------------------------------------
__global__ __launch_bounds__(256) void topk_lse_kernel(
    const float* __restrict__ logits,   // [2, B, A]
    const int* __restrict__ avail,      // [B, A] (bool as int32)
    const float* __restrict__ alpha_p,  // [1]
    float* __restrict__ out)            // [2*B]: v1 then v2
{
    const int row  = blockIdx.x * 4 + (threadIdx.x >> 6);  // 0..63 = h*32+b
    const int lane = threadIdx.x & 63;
    const int b    = row & 31;

    const float* x = logits + (size_t)row * NACT;
    float v[32];
    #pragma unroll
    for (int k = 0; k < 32; ++k) v[k] = x[k * 64 + lane];  // coalesced

    const float alpha = alpha_p[0];
    float smax = 0.f, ssum = 0.f;

    for (int it = 0; it < TOPK; ++it) {
        float best = -INFINITY; int bi = 1 << 30;
        #pragma unroll
        for (int k = 0; k < 32; ++k) {
            float val = v[k];
            if (val > best) { best = val; bi = k * 64 + lane; }
        }
        #pragma unroll
        for (int off = 32; off >= 1; off >>= 1) {
            float v2 = __shfl_xor(best, off, 64);
            int   i2 = __shfl_xor(bi,   off, 64);
            if (v2 > best || (v2 == best && i2 < bi)) { best = v2; bi = i2; }
        }
        if (it == 0) smax = best;                 // unmasked global max
        if (avail[(size_t)b * NACT + bi])         // broadcast load
            ssum += expf((best - smax) / alpha);
        #pragma unroll
        for (int k = 0; k < 32; ++k)              // extract without dyn-index
            if (k * 64 + lane == bi) v[k] = -INFINITY;
    }

    if (lane == 0)
        out[row] = smax + alpha * logf(fmaxf(ssum, 1e-10f));
}

// ---------------------------------------------------------------------------
extern "C" void kernel_launch(void* const* d_in, const int* in_sizes, int n_in,
                              void* d_out, int out_size, void* d_ws, size_t ws_size,
                              hipStream_t stream) {
    const float* s_embed = (const float*)d_in[0];   // [32, 2048] fp32
    const float* a_emb   = (const float*)d_in[1];   // [32, 2048, 2048] fp32
    const int*   avail   = (const int*)d_in[2];     // [32, 2048] bool->int32
    const float* alpha   = (const float*)d_in[3];   // [1] fp32
    float*       out     = (float*)d_out;           // [64] fp32 (v1 ++ v2)
    float*       logits  = (float*)d_ws;            // [2, 32, 2048] = 512 KB

    logits_kernel<<<BATCH * (NACT / ACTIONS_PER_BLOCK), 256, 0, stream>>>(
        s_embed, a_emb, logits);
    topk_lse_kernel<<<16, 256, 0, stream>>>(logits, avail, alpha, out);
}

// Round 3
// 686.127 us; speedup vs baseline: 1.2682x; 1.2682x over previous
//
#include <hip/hip_runtime.h>
#include <math.h>

// Problem: B=32, A=2048, D2=2048 (two heads of D=1024), TOP_K=5, fp32.
// a_embeds_target = 512 MB read per call >> all else -> HBM-bound.
// Roofline: 537 MB / 6.3 TB/s ~= 86 us for kernel 1; kernel 2 reads 768 KB.
//
// SESSION LEDGER (keep — this is the journal):
// R1: dur_us includes ~575 us harness reset: 2 GiB ws 0xAA fill ~330 us
//     [counter-verified at 6.5 TB/s] + 512 MB d_in restore ~245 us
//     (read+write ~1 GB of traffic).
// R2: pipeline+nt rewrite vs monolithic unroll = -7 us (neutral).
// R3 MEASUREMENT: ran the 512 MB stream 4x in one dispatch (batch-rotated).
//     Marginal cost per extra pass = (870-677)/3 = 64 us => streaming loop
//     sustains ~8 TB/s effective (partial LLC hits on rotated passes).
//     => kernel 1 single-pass is AT the HBM ceiling (~90 us incl. cold
//     start), NOT capped at 3 TB/s. The R1 "185 us residual" was a
//     restore-cost underestimate. Accounting closes:
//     677 = 330 (fill) + ~245 (restore) + ~90 (k1) + ~5 (k2+gaps).
// R4: revert measurement scaffolding; kernel time ~90 us vs 86 us roofline
//     => ROOFLINE. Only a semantic change (not re-reading a_embeds_target)
//     could go faster, and the reference requires the full reduction.
#define BATCH 32
#define NACT  2048
#define DIM2  2048   // 2*D
#define TOPK  5
#define ACTIONS_PER_BLOCK 32   // 4 waves x 8 actions
#define APW   8                // actions per wave

typedef float floatx4 __attribute__((ext_vector_type(4)));

// ---------------------------------------------------------------------------
// Kernel 1: logits[h][b][a] = dot(s[b, hD:(h+1)D], a_emb[b, a, hD:(h+1)D]).
// One wave per 8 actions. Lane l owns columns l*4 + 256*i (i=0..7) as float4.
// 2-deep double-buffered pipeline (8 loads in flight/wave, bounded VGPR),
// nontemporal stream loads (read-once data, no cache allocation), butterfly
// reductions deferred to the end as 16 independent chains.
// Counter-verified (R3) to stream at the memory-system ceiling.
// ---------------------------------------------------------------------------
__global__ __launch_bounds__(256) void logits_kernel(
    const float* __restrict__ s_embed,   // [B, DIM2]
    const float* __restrict__ a_emb,     // [B, A, DIM2]
    float* __restrict__ logits)          // [2, B, A] in workspace
{
    const int tile  = blockIdx.x;                 // 32*64 tiles
    const int b     = tile >> 6;                  // NACT/ACTIONS_PER_BLOCK=64
    const int a0    = (tile & 63) * ACTIONS_PER_BLOCK;
    const int wave  = threadIdx.x >> 6;
    const int lane  = threadIdx.x & 63;

    // s_embed[b] fragment for this lane: 8 x float4 = 32 floats in VGPRs.
    floatx4 sreg[8];
    const float* srow = s_embed + (size_t)b * DIM2 + lane * 4;
    #pragma unroll
    for (int i = 0; i < 8; ++i)
        sreg[i] = *(const floatx4*)(srow + 256 * i);

    const int abase = a0 + wave * APW;
    const float* pbase = a_emb + ((size_t)b * NACT + abase) * DIM2 + lane * 4;

    float acc1[APW], acc2[APW];
    floatx4 bufA[8], bufB[8];   // named buffers: all indices fold after unroll

    // Prologue: issue action 0's 8 loads.
    #pragma unroll
    for (int i = 0; i < 8; ++i)
        bufA[i] = __builtin_nontemporal_load((const floatx4*)(pbase + 256 * i));

    #pragma unroll
    for (int j = 0; j < APW; ++j) {
        const floatx4* cur = (j & 1) ? bufB : bufA;   // folds after unroll
        floatx4*       nxt = (j & 1) ? bufA : bufB;

        // Issue next action's loads BEFORE consuming current buffer:
        // keeps 8 loads in flight across the waitcnt.
        if (j + 1 < APW) {
            const float* pn = pbase + (size_t)(j + 1) * DIM2;
            #pragma unroll
            for (int i = 0; i < 8; ++i)
                nxt[i] = __builtin_nontemporal_load((const floatx4*)(pn + 256 * i));
        }

        float d1 = 0.f, d2 = 0.f;
        #pragma unroll
        for (int i = 0; i < 4; ++i) {                 // head 1: cols [0,1024)
            floatx4 v = cur[i];
            d1 += v.x * sreg[i].x + v.y * sreg[i].y + v.z * sreg[i].z + v.w * sreg[i].w;
        }
        #pragma unroll
        for (int i = 4; i < 8; ++i) {                 // head 2: cols [1024,2048)
            floatx4 v = cur[i];
            d2 += v.x * sreg[i].x + v.y * sreg[i].y + v.z * sreg[i].z + v.w * sreg[i].w;
        }
        acc1[j] = d1;
        acc2[j] = d2;
    }

    // Batched butterfly reductions: 16 independent chains.
    #pragma unroll
    for (int off = 32; off >= 1; off >>= 1) {
        #pragma unroll
        for (int j = 0; j < APW; ++j) {
            acc1[j] += __shfl_xor(acc1[j], off, 64);
            acc2[j] += __shfl_xor(acc2[j], off, 64);
        }
    }

    if (lane == 0) {
        float* o1 = logits + (size_t)b * NACT + abase;
        float* o2 = o1 + (size_t)BATCH * NACT;
        #pragma unroll
        for (int j = 0; j < APW; ++j) { o1[j] = acc1[j]; o2[j] = acc2[j]; }
    }
}

// ---------------------------------------------------------------------------
// Kernel 2: one wave per (head,row). Row (2048 floats) lives in registers
// (32/lane, strided: lane l holds elements 64k+l). 5x shfl-argmax with
// lowest-index tie-break (matches jax.lax.top_k), then masked LSE with
// UNMASKED-max stabilizer and eps clamp:
//   out = maxlogit + alpha * log(max(sum_{top5 & avail} exp((x-maxlogit)/alpha), 1e-10))
// No LDS, no __syncthreads.
// ---------------------------------------------------------------------------
__global__ __launch_bounds__(256) void topk_lse_kernel(
    const float* __restrict__ logits,   // [2, B, A]
    const int* __restrict__ avail,      // [B, A] (bool as int32)
    const float* __restrict__ alpha_p,  // [1]
    float* __restrict__ out)            // [2*B]: v1 then v2
{
    const int row  = blockIdx.x * 4 + (threadIdx.x >> 6);  // 0..63 = h*32+b
    const int lane = threadIdx.x & 63;
    const int b    = row & 31;

    const float* x = logits + (size_t)row * NACT;
    float v[32];
    #pragma unroll
    for (int k = 0; k < 32; ++k) v[k] = x[k * 64 + lane];  // coalesced

    const float alpha = alpha_p[0];
    float smax = 0.f, ssum = 0.f;

    for (int it = 0; it < TOPK; ++it) {
        // lane-local argmax; k ascending + strict '>' keeps lowest index
        float best = -INFINITY; int bi = 1 << 30;
        #pragma unroll
        for (int k = 0; k < 32; ++k) {
            float val = v[k];
            if (val > best) { best = val; bi = k * 64 + lane; }
        }
        // wave argmax, tie -> lowest linear index
        #pragma unroll
        for (int off = 32; off >= 1; off >>= 1) {
            float v2 = __shfl_xor(best, off, 64);
            int   i2 = __shfl_xor(bi,   off, 64);
            if (v2 > best || (v2 == best && i2 < bi)) { best = v2; bi = i2; }
        }
        if (it == 0) smax = best;                 // unmasked global max
        if (avail[(size_t)b * NACT + bi])         // broadcast load
            ssum += expf((best - smax) / alpha);
        #pragma unroll
        for (int k = 0; k < 32; ++k)              // extract without dyn-index
            if (k * 64 + lane == bi) v[k] = -INFINITY;
    }

    if (lane == 0)
        out[row] = smax + alpha * logf(fmaxf(ssum, 1e-10f));
}

// ---------------------------------------------------------------------------
extern "C" void kernel_launch(void* const* d_in, const int* in_sizes, int n_in,
                              void* d_out, int out_size, void* d_ws, size_t ws_size,
                              hipStream_t stream) {
    const float* s_embed = (const float*)d_in[0];   // [32, 2048] fp32
    const float* a_emb   = (const float*)d_in[1];   // [32, 2048, 2048] fp32
    const int*   avail   = (const int*)d_in[2];     // [32, 2048] bool->int32
    const float* alpha   = (const float*)d_in[3];   // [1] fp32
    float*       out     = (float*)d_out;           // [64] fp32 (v1 ++ v2)
    float*       logits  = (float*)d_ws;            // [2, 32, 2048] = 512 KB

    logits_kernel<<<BATCH * (NACT / ACTIONS_PER_BLOCK), 256, 0, stream>>>(
        s_embed, a_emb, logits);
    topk_lse_kernel<<<16, 256, 0, stream>>>(logits, avail, alpha, out);
}